// Round 3
// baseline (23091.290 us; speedup 1.0000x reference)
//
#include <hip/hip_runtime.h>
#include <hip/hip_bf16.h>

// problem constants
#define kT 8
#define kD 128
#define kH 8
#define kHD 16
#define kFF 512
#define kL 6
#define kNADM 2048
#define kNLAB 753
#define kNDRUG 4294
#define kE 16384

// ---------------- node projections: out[n,d] = sum_k x[n,k]w[k,d] + b[d] (+ emb[nid[n],d]) ----------------
__global__ void proj_kernel(const float* __restrict__ x, int IK,
                            const float* __restrict__ w, const float* __restrict__ b,
                            const float* __restrict__ emb, const int* __restrict__ nid,
                            float* __restrict__ out) {
    int n = blockIdx.x, d = threadIdx.x;
    float acc = b[d];
    for (int k = 0; k < IK; ++k) acc += x[n * IK + k] * w[k * kD + d];
    if (emb) acc += emb[(long)nid[n] * kD + d];
    out[(long)n * kD + d] = acc;
}

// ---------------- GINE messages, both directions per edge (reverse edges reuse attrs) ----------------
// block = 128 threads = 1 edge (t,e). grid = kT*kE.
__global__ void msg_kernel(const float* __restrict__ ex, int ek,
                           const int* __restrict__ src, const int* __restrict__ dst,
                           const float* __restrict__ we, const float* __restrict__ be,
                           const float* __restrict__ hS, long hSstride,   // src-side states (adm)
                           const float* __restrict__ hD, long hDstride,   // dst-side states (lab/drug)
                           float* __restrict__ msgDst, int Ndst,          // fwd: relu(hS[src]+e) -> dst
                           float* __restrict__ msgSrc, int Nsrc) {        // rev: relu(hD[dst]+e) -> src
    int idx = blockIdx.x;           // t*kE + e
    int t = idx >> 14;              // kE == 2^14
    int d = threadIdx.x;
    int s = src[idx], dd = dst[idx];
    const float* exp_ = ex + (long)idx * ek;
    float e = be[d];
    for (int k = 0; k < ek; ++k) e += exp_[k] * we[k * kD + d];
    float vf = hS[t * hSstride + (long)s * kD + d] + e; if (vf < 0.f) vf = 0.f;
    atomicAdd(&msgDst[((long)t * Ndst + dd) * kD + d], vf);
    float vr = hD[t * hDstride + (long)dd * kD + d] + e; if (vr < 0.f) vr = 0.f;
    atomicAdd(&msgSrc[((long)t * Nsrc + s) * kD + d], vr);
}

__global__ void zero_kernel(float* __restrict__ p, long n) {
    long i = (long)blockIdx.x * blockDim.x + threadIdx.x;
    if (i < n) p[i] = 0.f;
}

// ---------------- GNN dense: out = relu((msg + h) @ W[t,l,type] + b) ----------------
__global__ void gnn_dense(const float* __restrict__ msg, const float* __restrict__ hin, long hinStride,
                          const float* __restrict__ gw, const float* __restrict__ gb,
                          int l, int type, float* __restrict__ out, int N) {
    int t = blockIdx.x / N, n = blockIdx.x % N, d = threadIdx.x;
    __shared__ float row[kD];
    long o = ((long)t * N + n) * kD;
    row[d] = msg[o + d] + hin[t * hinStride + (long)n * kD + d];
    __syncthreads();
    long wo = (((long)t * 2 + l) * 4 + type);
    const float* W = gw + wo * kD * kD;
    float acc = gb[wo * kD + d];
    for (int k = 0; k < kD; ++k) acc += row[k] * W[k * kD + d];
    out[o + d] = acc > 0.f ? acc : 0.f;
}

__global__ void gnn_dense_adm(const float* __restrict__ m1, const float* __restrict__ m2,
                              const float* __restrict__ hin, long hinStride,
                              const float* __restrict__ gw, const float* __restrict__ gb,
                              int l, float* __restrict__ out) {
    int t = blockIdx.x / kNADM, n = blockIdx.x % kNADM, d = threadIdx.x;
    __shared__ float r1[kD], r2[kD];
    long o = ((long)t * kNADM + n) * kD;
    float h = hin[t * hinStride + (long)n * kD + d];
    r1[d] = m1[o + d] + h;
    r2[d] = m2[o + d] + h;
    __syncthreads();
    long w1o = (((long)t * 2 + l) * 4 + 1), w3o = (((long)t * 2 + l) * 4 + 3);
    const float* W1 = gw + w1o * kD * kD;
    const float* W3 = gw + w3o * kD * kD;
    float acc = gb[w1o * kD + d] + gb[w3o * kD + d];
    for (int k = 0; k < kD; ++k) acc += r1[k] * W1[k * kD + d] + r2[k] * W3[k * kD + d];
    out[o + d] = acc > 0.f ? acc : 0.f;
}

// ---------------- sinusoidal PE add (in place), grid = kT*N blocks of 128 ----------------
__global__ void pe_kernel(float* __restrict__ x, int N) {
    int t = blockIdx.x / N, d = threadIdx.x;
    long o = (long)blockIdx.x * kD + d;
    float ang = (float)t * __expf(-(float)(d & ~1) * (9.210340371976184f / 128.f));
    x[o] += (d & 1) ? cosf(ang) : sinf(ang);
}

__global__ void copy_kernel(float* __restrict__ dst, const float* __restrict__ src, long n) {
    long i = (long)blockIdx.x * blockDim.x + threadIdx.x;
    if (i < n) dst[i] = src[i];
}

// ---------------- row-block GEMM: C[M,Nc] = A[M,K] @ W[K,Nc] + bias, optional relu ----------------
template<int R, int KMAX>
__global__ void gemm_rows(const float* __restrict__ A, int lda, int K,
                          const float* __restrict__ W, int ldw,
                          const float* __restrict__ bias,
                          float* __restrict__ C, int ldc, int M, int Nc, int doRelu) {
    __shared__ float a[R][KMAX];
    int rowBase = blockIdx.x * R;
#pragma unroll
    for (int r = 0; r < R; ++r) {
        int row = rowBase + r;
        for (int k = threadIdx.x; k < K; k += 128)
            a[r][k] = (row < M) ? A[(long)row * lda + k] : 0.f;
    }
    __syncthreads();
    for (int c = threadIdx.x; c < Nc; c += 128) {
        float bv = bias[c];
        float acc[R];
#pragma unroll
        for (int r = 0; r < R; ++r) acc[r] = bv;
        for (int k = 0; k < K; ++k) {
            float w = W[(long)k * ldw + c];
#pragma unroll
            for (int r = 0; r < R; ++r) acc[r] += a[r][k] * w;
        }
#pragma unroll
        for (int r = 0; r < R; ++r) {
            int row = rowBase + r;
            if (row < M) {
                float v = acc[r];
                if (doRelu && v < 0.f) v = 0.f;
                C[(long)row * ldc + c] = v;
            }
        }
    }
}

// ---------------- per-node causal attention over T=8, H=8, HD=16 ----------------
__global__ void attn_kernel(const float* __restrict__ qkv, float* __restrict__ o, int N) {
    int idx = blockIdx.x * blockDim.x + threadIdx.x;
    if (idx >= N * kH * kT) return;
    int n = idx / (kH * kT);
    int r = idx % (kH * kT);
    int h = r / kT, s = r % kT;
    const float* qp = qkv + ((long)s * N + n) * 384 + h * kHD;
    float q[kHD];
#pragma unroll
    for (int j = 0; j < kHD; ++j) q[j] = qp[j];
    float sc[kT];
    float mx = -1e30f;
    for (int m = 0; m <= s; ++m) {
        const float* kp = qkv + ((long)m * N + n) * 384 + 128 + h * kHD;
        float dacc = 0.f;
#pragma unroll
        for (int j = 0; j < kHD; ++j) dacc += q[j] * kp[j];
        dacc *= 0.25f;
        sc[m] = dacc;
        mx = fmaxf(mx, dacc);
    }
    float sum = 0.f;
    for (int m = 0; m <= s; ++m) { sc[m] = expf(sc[m] - mx); sum += sc[m]; }
    float inv = 1.f / sum;
    float ov[kHD];
#pragma unroll
    for (int j = 0; j < kHD; ++j) ov[j] = 0.f;
    for (int m = 0; m <= s; ++m) {
        const float* vp = qkv + ((long)m * N + n) * 384 + 256 + h * kHD;
        float am = sc[m] * inv;
#pragma unroll
        for (int j = 0; j < kHD; ++j) ov[j] += am * vp[j];
    }
    float* op = o + ((long)s * N + n) * kD + h * kHD;
#pragma unroll
    for (int j = 0; j < kHD; ++j) op[j] = ov[j];
}

// ---------------- x = LN(x + y) * g + b, one block per row ----------------
__global__ void res_ln_kernel(float* __restrict__ x, const float* __restrict__ y,
                              const float* __restrict__ g, const float* __restrict__ b) {
    int d = threadIdx.x;
    long o = (long)blockIdx.x * kD + d;
    __shared__ float red[kD];
    float v = x[o] + y[o];
    red[d] = v;
    __syncthreads();
    for (int st = 64; st > 0; st >>= 1) { if (d < st) red[d] += red[d + st]; __syncthreads(); }
    float mu = red[0] * (1.f / kD);
    __syncthreads();
    float dv = v - mu;
    red[d] = dv * dv;
    __syncthreads();
    for (int st = 64; st > 0; st >>= 1) { if (d < st) red[d] += red[d + st]; __syncthreads(); }
    float var = red[0] * (1.f / kD);
    x[o] = dv * rsqrtf(var + 1e-5f) * g[d] + b[d];
}

// ---------------- scores[t,n,m] = A[t,n,:] . B[t,m,:]  (16x16 tiles) ----------------
__global__ void score_kernel(const float* __restrict__ A, const float* __restrict__ B,
                             float* __restrict__ out, int M, int Nn) {
    int t = blockIdx.z;
    const float* At = A + (long)t * M * kD;
    const float* Bt = B + (long)t * Nn * kD;
    float* Ot = out + (long)t * M * Nn;
    int bm = blockIdx.y * 16, bn = blockIdx.x * 16;
    int ty = threadIdx.y, tx = threadIdx.x;
    __shared__ float As[16][17], Bs[16][17];
    float acc = 0.f;
    for (int k0 = 0; k0 < kD; k0 += 16) {
        int am = bm + ty;
        As[ty][tx] = (am < M) ? At[(long)am * kD + k0 + tx] : 0.f;
        int bnn = bn + ty;
        Bs[ty][tx] = (bnn < Nn) ? Bt[(long)bnn * kD + k0 + tx] : 0.f;
        __syncthreads();
#pragma unroll
        for (int k = 0; k < 16; ++k) acc += As[ty][k] * Bs[tx][k];
        __syncthreads();
    }
    int om = bm + ty, on = bn + tx;
    if (om < M && on < Nn) Ot[(long)om * Nn + on] = acc;
}

// ---------------- labels scatter: out[t, s, d] = 1 ----------------
__global__ void label_kernel(const int* __restrict__ s_, const int* __restrict__ d_,
                             float* __restrict__ out, int Nn) {
    int idx = blockIdx.x * blockDim.x + threadIdx.x;
    if (idx >= kT * kE) return;
    int t = idx >> 14;
    int s = s_[idx], dd = d_[idx];
    out[(long)t * kNADM * Nn + (long)s * Nn + dd] = 1.0f;
}

extern "C" void kernel_launch(void* const* d_in, const int* in_sizes, int n_in,
                              void* d_out, int out_size, void* d_ws, size_t ws_size,
                              hipStream_t stream) {
    // ---- inputs (reference dtypes: float32 / int32) ----
    const float* x_adm       = (const float*)d_in[0];
    const float* x_lab       = (const float*)d_in[1];
    const float* x_drug      = (const float*)d_in[2];
    const float* edge_x_did  = (const float*)d_in[3];
    const float* edge_x_took = (const float*)d_in[4];
    const float* w_proj_adm  = (const float*)d_in[5];
    const float* b_proj_adm  = (const float*)d_in[6];
    const float* w_proj_lab  = (const float*)d_in[7];
    const float* b_proj_lab  = (const float*)d_in[8];
    const float* w_proj_drug = (const float*)d_in[9];
    const float* b_proj_drug = (const float*)d_in[10];
    const float* w_proj_e    = (const float*)d_in[11];
    const float* b_proj_e    = (const float*)d_in[12];
    const float* w_proj_e4d  = (const float*)d_in[13];
    const float* b_proj_e4d  = (const float*)d_in[14];
    const float* emb_lab     = (const float*)d_in[15];
    const float* emb_drug    = (const float*)d_in[16];
    const float* gnn_w       = (const float*)d_in[17];
    const float* gnn_b       = (const float*)d_in[18];
    const float* dec_sa_in_w  = (const float*)d_in[19];
    const float* dec_sa_in_b  = (const float*)d_in[20];
    const float* dec_sa_out_w = (const float*)d_in[21];
    const float* dec_sa_out_b = (const float*)d_in[22];
    const float* dec_ca_in_w  = (const float*)d_in[23];
    const float* dec_ca_in_b  = (const float*)d_in[24];
    const float* dec_ca_out_w = (const float*)d_in[25];
    const float* dec_ca_out_b = (const float*)d_in[26];
    const float* dec_ff1_w    = (const float*)d_in[27];
    const float* dec_ff1_b    = (const float*)d_in[28];
    const float* dec_ff2_w    = (const float*)d_in[29];
    const float* dec_ff2_b    = (const float*)d_in[30];
    const float* dec_ln1_w    = (const float*)d_in[31];
    const float* dec_ln1_b    = (const float*)d_in[32];
    const float* dec_ln2_w    = (const float*)d_in[33];
    const float* dec_ln2_b    = (const float*)d_in[34];
    const float* dec_ln3_w    = (const float*)d_in[35];
    const float* dec_ln3_b    = (const float*)d_in[36];
    const int* node_id_lab  = (const int*)d_in[37];
    const int* node_id_drug = (const int*)d_in[38];
    const int* src_did      = (const int*)d_in[39];
    const int* dst_did      = (const int*)d_in[40];
    const int* src_took     = (const int*)d_in[41];
    const int* dst_took     = (const int*)d_in[42];
    const int* lbl_src_did  = (const int*)d_in[43];
    const int* lbl_dst_did  = (const int*)d_in[44];
    const int* lbl_src_took = (const int*)d_in[45];
    const int* lbl_dst_took = (const int*)d_in[46];

    float* out_f = (float*)d_out;
    const long SC1 = (long)kT * kNADM * kNLAB;    // 12,337,152
    const long SC2 = (long)kT * kNADM * kNDRUG;   // 70,352,896
    float* out_scores  = out_f;
    float* out_labels  = out_f + SC1;
    float* out_scores4 = out_f + 2 * SC1;
    float* out_labels4 = out_f + 2 * SC1 + SC2;

    // ---- scratch arena inside d_out: scores4drug + labels4drug regions (2*SC2 floats).
    // scores4 is written second-to-last (over SCR, dead by then); labels4 memset+scatter
    // runs last (over Sa/Sl/Sd, dead by then).
    float* SCR = out_scores4;                     // SC2 = 70.3M floats available, peak use 26.4M
    float* Sp  = out_labels4;                     // persistent states live in labels4 region
    const long SA_SZ = (long)kT * kNADM * kD;     // 2,097,152
    const long SL_SZ = (long)kT * kNLAB * kD;     //   771,072
    const long SD_SZ = (long)kT * kNDRUG * kD;    // 4,397,056
    float* Sa = Sp;
    float* Sl = Sa + SA_SZ;
    float* Sd = Sl + SL_SZ;                       // ends at 7,265,280 < SC2
    // GNN-phase aliases in SCR
    float* h0a = SCR;                               // 2048*128
    float* h0l = h0a + (long)kNADM * kD;            //  753*128
    float* h0d = h0l + (long)kNLAB * kD;            // 4294*128
    float* Ta  = h0d + (long)kNDRUG * kD;
    float* Tl  = Ta + SA_SZ;
    float* Td  = Tl + SL_SZ;
    float* msgA1 = Td + SD_SZ;
    float* msgA2 = msgA1 + SA_SZ;
    float* msgL  = msgA2 + SA_SZ;
    float* msgD  = msgL + SL_SZ;
    const long MSG_SZ = SA_SZ * 2 + SL_SZ + SD_SZ;  // 9,362,432
    // decoder-phase aliases in SCR (GNN buffers dead by then)
    float* bigbuf = SCR;                            // kT*kNDRUG*512 = 17,588,224
    float* obuf   = bigbuf + (long)kT * kNDRUG * kFF;
    float* membuf = obuf + SD_SZ;                   // ends at 26,382,336 < SC2

    // ---- node projections ----
    proj_kernel<<<kNADM,  kD, 0, stream>>>(x_adm,  8, w_proj_adm,  b_proj_adm,  nullptr,  nullptr,      h0a);
    proj_kernel<<<kNLAB,  kD, 0, stream>>>(x_lab,  2, w_proj_lab,  b_proj_lab,  emb_lab,  node_id_lab,  h0l);
    proj_kernel<<<kNDRUG, kD, 0, stream>>>(x_drug, 8, w_proj_drug, b_proj_drug, emb_drug, node_id_drug, h0d);

    // ---- GNN: 2 layers ----
    for (int l = 0; l < 2; ++l) {
        zero_kernel<<<(int)((MSG_SZ + 255) / 256), 256, 0, stream>>>(msgA1, MSG_SZ);
        const float *ha, *hl, *hd;
        long sa, sl, sd;
        float *oa, *ol, *od;
        if (l == 0) { ha = h0a; hl = h0l; hd = h0d; sa = sl = sd = 0;
                      oa = Ta; ol = Tl; od = Td; }
        else        { ha = Ta; hl = Tl; hd = Td;
                      sa = (long)kNADM * kD; sl = (long)kNLAB * kD; sd = (long)kNDRUG * kD;
                      oa = Sa; ol = Sl; od = Sd; }
        msg_kernel<<<kT * kE, kD, 0, stream>>>(edge_x_did, 2, src_did, dst_did, w_proj_e, b_proj_e,
                                               ha, sa, hl, sl, msgL, kNLAB, msgA1, kNADM);
        msg_kernel<<<kT * kE, kD, 0, stream>>>(edge_x_took, 7, src_took, dst_took, w_proj_e4d, b_proj_e4d,
                                               ha, sa, hd, sd, msgD, kNDRUG, msgA2, kNADM);
        gnn_dense_adm<<<kT * kNADM, kD, 0, stream>>>(msgA1, msgA2, ha, sa, gnn_w, gnn_b, l, oa);
        gnn_dense<<<kT * kNLAB,  kD, 0, stream>>>(msgL, hl, sl, gnn_w, gnn_b, l, 0, ol, kNLAB);
        gnn_dense<<<kT * kNDRUG, kD, 0, stream>>>(msgD, hd, sd, gnn_w, gnn_b, l, 2, od, kNDRUG);
    }

    // ---- positional encoding ----
    pe_kernel<<<kT * kNADM,  kD, 0, stream>>>(Sa, kNADM);
    pe_kernel<<<kT * kNLAB,  kD, 0, stream>>>(Sl, kNLAB);
    pe_kernel<<<kT * kNDRUG, kD, 0, stream>>>(Sd, kNDRUG);

    // ---- decoders ----
    auto run_decoder = [&](int i, float* X, int N) {
        long TN = (long)kT * N;
        long n128 = TN * kD;
        int gRows = (int)((TN + 7) / 8);
        copy_kernel<<<(int)((n128 + 255) / 256), 256, 0, stream>>>(membuf, X, n128);
        for (int l = 0; l < kL; ++l) {
            long w = (long)i * kL + l;
            // self-attention
            gemm_rows<8, 128><<<gRows, 128, 0, stream>>>(X, kD, kD, dec_sa_in_w + w * kD * 384, 384,
                                                         dec_sa_in_b + w * 384, bigbuf, 384, (int)TN, 384, 0);
            attn_kernel<<<(N * kH * kT + 255) / 256, 256, 0, stream>>>(bigbuf, obuf, N);
            gemm_rows<8, 128><<<gRows, 128, 0, stream>>>(obuf, kD, kD, dec_sa_out_w + w * kD * kD, kD,
                                                         dec_sa_out_b + w * kD, bigbuf, kD, (int)TN, kD, 0);
            res_ln_kernel<<<(int)TN, kD, 0, stream>>>(X, bigbuf, dec_ln1_w + w * kD, dec_ln1_b + w * kD);
            // cross-attention (q from x, k/v from mem)
            gemm_rows<8, 128><<<gRows, 128, 0, stream>>>(X, kD, kD, dec_ca_in_w + w * kD * 384, 384,
                                                         dec_ca_in_b + w * 384, bigbuf, 384, (int)TN, 128, 0);
            gemm_rows<8, 128><<<gRows, 128, 0, stream>>>(membuf, kD, kD, dec_ca_in_w + w * kD * 384 + 128, 384,
                                                         dec_ca_in_b + w * 384 + 128, bigbuf + 128, 384, (int)TN, 256, 0);
            attn_kernel<<<(N * kH * kT + 255) / 256, 256, 0, stream>>>(bigbuf, obuf, N);
            gemm_rows<8, 128><<<gRows, 128, 0, stream>>>(obuf, kD, kD, dec_ca_out_w + w * kD * kD, kD,
                                                         dec_ca_out_b + w * kD, bigbuf, kD, (int)TN, kD, 0);
            res_ln_kernel<<<(int)TN, kD, 0, stream>>>(X, bigbuf, dec_ln2_w + w * kD, dec_ln2_b + w * kD);
            // feed-forward
            gemm_rows<8, 128><<<gRows, 128, 0, stream>>>(X, kD, kD, dec_ff1_w + w * kD * kFF, kFF,
                                                         dec_ff1_b + w * kFF, bigbuf, kFF, (int)TN, kFF, 1);
            gemm_rows<8, 512><<<gRows, 128, 0, stream>>>(bigbuf, kFF, kFF, dec_ff2_w + w * kFF * kD, kD,
                                                         dec_ff2_b + w * kD, obuf, kD, (int)TN, kD, 0);
            res_ln_kernel<<<(int)TN, kD, 0, stream>>>(X, obuf, dec_ln3_w + w * kD, dec_ln3_b + w * kD);
        }
    };

    dim3 blk16(16, 16);
    run_decoder(0, Sa, kNADM);
    run_decoder(1, Sl, kNLAB);
    run_decoder(2, Sd, kNDRUG);

    // scores (adm x lab) -> dedicated region
    score_kernel<<<dim3((kNLAB + 15) / 16, kNADM / 16, kT), blk16, 0, stream>>>(Sa, Sl, out_scores, kNADM, kNLAB);
    // labels (did)
    hipMemsetAsync((void*)out_labels, 0, (size_t)SC1 * sizeof(float), stream);
    label_kernel<<<(kT * kE + 255) / 256, 256, 0, stream>>>(lbl_src_did, lbl_dst_did, out_labels, kNLAB);
    // scores4 (adm x drug): writes over SCR (dead), reads Sa/Sd in labels4 region — disjoint
    score_kernel<<<dim3((kNDRUG + 15) / 16, kNADM / 16, kT), blk16, 0, stream>>>(Sa, Sd, out_scores4, kNADM, kNDRUG);
    // labels4 LAST (its memset clobbers Sa/Sl/Sd, which are dead now)
    hipMemsetAsync((void*)out_labels4, 0, (size_t)SC2 * sizeof(float), stream);
    label_kernel<<<(kT * kE + 255) / 256, 256, 0, stream>>>(lbl_src_took, lbl_dst_took, out_labels4, kNDRUG);

    (void)in_sizes; (void)n_in; (void)out_size; (void)d_ws; (void)ws_size;
}

// Round 4
// 6451.694 us; speedup vs baseline: 3.5791x; 3.5791x over previous
//
#include <hip/hip_runtime.h>
#include <hip/hip_bf16.h>

// problem constants
#define kT 8
#define kD 128
#define kH 8
#define kHD 16
#define kFF 512
#define kL 6
#define kNADM 2048
#define kNLAB 753
#define kNDRUG 4294
#define kE 16384

typedef __attribute__((ext_vector_type(8))) short short8;
typedef __attribute__((ext_vector_type(4))) float floatx4;

// round-to-nearest-even fp32 -> bf16 bits
__device__ __forceinline__ unsigned short f2b(float f) {
    unsigned x = __float_as_uint(f);
    unsigned r = (x + 0x7fffu + ((x >> 16) & 1u)) >> 16;
    return (unsigned short)r;
}

// ---------------- node projections ----------------
__global__ void proj_kernel(const float* __restrict__ x, int IK,
                            const float* __restrict__ w, const float* __restrict__ b,
                            const float* __restrict__ emb, const int* __restrict__ nid,
                            float* __restrict__ out) {
    int n = blockIdx.x, d = threadIdx.x;
    float acc = b[d];
    for (int k = 0; k < IK; ++k) acc += x[n * IK + k] * w[k * kD + d];
    if (emb) acc += emb[(long)nid[n] * kD + d];
    out[(long)n * kD + d] = acc;
}

// ---------------- GINE messages (both directions per edge) ----------------
__global__ void msg_kernel(const float* __restrict__ ex, int ek,
                           const int* __restrict__ src, const int* __restrict__ dst,
                           const float* __restrict__ we, const float* __restrict__ be,
                           const float* __restrict__ hS, long hSstride,
                           const float* __restrict__ hD, long hDstride,
                           float* __restrict__ msgDst, int Ndst,
                           float* __restrict__ msgSrc, int Nsrc) {
    int idx = blockIdx.x;
    int t = idx >> 14;
    int d = threadIdx.x;
    int s = src[idx], dd = dst[idx];
    const float* exp_ = ex + (long)idx * ek;
    float e = be[d];
    for (int k = 0; k < ek; ++k) e += exp_[k] * we[k * kD + d];
    float vf = hS[t * hSstride + (long)s * kD + d] + e; if (vf < 0.f) vf = 0.f;
    atomicAdd(&msgDst[((long)t * Ndst + dd) * kD + d], vf);
    float vr = hD[t * hDstride + (long)dd * kD + d] + e; if (vr < 0.f) vr = 0.f;
    atomicAdd(&msgSrc[((long)t * Nsrc + s) * kD + d], vr);
}

__global__ void zero_kernel(float* __restrict__ p, long n) {
    long i = (long)blockIdx.x * blockDim.x + threadIdx.x;
    if (i < n) p[i] = 0.f;
}

// ---------------- GNN dense ----------------
__global__ void gnn_dense(const float* __restrict__ msg, const float* __restrict__ hin, long hinStride,
                          const float* __restrict__ gw, const float* __restrict__ gb,
                          int l, int type, float* __restrict__ out, int N) {
    int t = blockIdx.x / N, n = blockIdx.x % N, d = threadIdx.x;
    __shared__ float row[kD];
    long o = ((long)t * N + n) * kD;
    row[d] = msg[o + d] + hin[t * hinStride + (long)n * kD + d];
    __syncthreads();
    long wo = (((long)t * 2 + l) * 4 + type);
    const float* W = gw + wo * kD * kD;
    float acc = gb[wo * kD + d];
    for (int k = 0; k < kD; ++k) acc += row[k] * W[k * kD + d];
    out[o + d] = acc > 0.f ? acc : 0.f;
}

__global__ void gnn_dense_adm(const float* __restrict__ m1, const float* __restrict__ m2,
                              const float* __restrict__ hin, long hinStride,
                              const float* __restrict__ gw, const float* __restrict__ gb,
                              int l, float* __restrict__ out) {
    int t = blockIdx.x / kNADM, n = blockIdx.x % kNADM, d = threadIdx.x;
    __shared__ float r1[kD], r2[kD];
    long o = ((long)t * kNADM + n) * kD;
    float h = hin[t * hinStride + (long)n * kD + d];
    r1[d] = m1[o + d] + h;
    r2[d] = m2[o + d] + h;
    __syncthreads();
    long w1o = (((long)t * 2 + l) * 4 + 1), w3o = (((long)t * 2 + l) * 4 + 3);
    const float* W1 = gw + w1o * kD * kD;
    const float* W3 = gw + w3o * kD * kD;
    float acc = gb[w1o * kD + d] + gb[w3o * kD + d];
    for (int k = 0; k < kD; ++k) acc += r1[k] * W1[k * kD + d] + r2[k] * W3[k * kD + d];
    out[o + d] = acc > 0.f ? acc : 0.f;
}

// ---------------- sinusoidal PE ----------------
__global__ void pe_kernel(float* __restrict__ x, int N) {
    int t = blockIdx.x / N, d = threadIdx.x;
    long o = (long)blockIdx.x * kD + d;
    float ang = (float)t * expf(-(float)(d & ~1) * (9.210340371976184f / 128.f));
    x[o] += (d & 1) ? cosf(ang) : sinf(ang);
}

__global__ void copy_kernel(float* __restrict__ dst, const float* __restrict__ src, long n) {
    long i = (long)blockIdx.x * blockDim.x + threadIdx.x;
    if (i < n) dst[i] = src[i];
}

// ---------------- weight pack: fp32 [slices][K][N] -> bf16 B-fragment order ----------------
// for (k,n): tile=n>>4, kcg=k>>5, quad=(k>>3)&3, j=k&7, lane=quad*16+(n&15)
// pidx = ((tile*(K/32)+kcg)*64+lane)*8+j
__global__ void pack_w(const float* __restrict__ W, short* __restrict__ out,
                       int K, int N, long total) {
    long idx = (long)blockIdx.x * blockDim.x + threadIdx.x;
    if (idx >= total) return;
    long per = (long)K * N;
    long s = idx / per, r = idx % per;
    int k = (int)(r / N), n = (int)(r % N);
    int tile = n >> 4, kcg = k >> 5, quad = (k >> 3) & 3, j = k & 7;
    int lane = quad * 16 + (n & 15);
    long pidx = (((long)tile * (K >> 5) + kcg) * 64 + lane) * 8 + j;
    out[s * per + pidx] = (short)f2b(W[idx]);
}

// ---------------- MFMA GEMM: C[M,N] = A[M,K]fp32 @ Wpacked(bf16) + bias, opt relu ----------------
// block 256 thr = 4 waves; M-tile 64 (wave w handles rows w*16..w*16+15); all waves sweep all N col-tiles.
template<int K, int N, bool RELU>
__global__ __launch_bounds__(256) void mfma_gemm(const float* __restrict__ A,
                                                 const short* __restrict__ Bp,
                                                 const float* __restrict__ bias,
                                                 float* __restrict__ C, int ldc, int M) {
    constexpr int KS = (K > 128) ? 128 : K;    // staged K per round
    constexpr int KB = K / KS;                 // staging rounds
    constexpr int NT = N / 16;                 // col tiles
    constexpr int NA = (KB > 1) ? NT : 1;      // accumulator tiles held
    constexpr int PITCH = KS + 8;              // shorts per LDS row (16B-aligned, conflict-free)
    __shared__ short Alds[64 * PITCH];
    int m0 = blockIdx.x * 64;
    int tid = threadIdx.x;
    int wave = tid >> 6, lane = tid & 63;
    int lrow = lane & 15, quad = lane >> 4;

    floatx4 acc[NA];
#pragma unroll
    for (int i = 0; i < NA; ++i) acc[i] = (floatx4){0.f, 0.f, 0.f, 0.f};

    for (int kb = 0; kb < KB; ++kb) {
        if (kb) __syncthreads();
        // stage A[m0..m0+63][kb*KS..+KS) -> bf16 LDS
        for (int i = tid; i < 64 * (KS / 2); i += 256) {
            int r = i / (KS / 2), kp = i % (KS / 2);
            int row = m0 + r;
            float2 v = make_float2(0.f, 0.f);
            if (row < M) v = *(const float2*)&A[(long)row * K + kb * KS + 2 * kp];
            unsigned u = (unsigned)f2b(v.x) | ((unsigned)f2b(v.y) << 16);
            *(unsigned*)&Alds[r * PITCH + 2 * kp] = u;
        }
        __syncthreads();

        for (int nt = 0; nt < NT; ++nt) {
            int ai = (KB > 1) ? nt : 0;
            if (KB == 1) acc[0] = (floatx4){0.f, 0.f, 0.f, 0.f};
#pragma unroll
            for (int kc = 0; kc < KS / 32; ++kc) {
                short8 a = *(const short8*)&Alds[(wave * 16 + lrow) * PITCH + kc * 32 + quad * 8];
                int kcg = kb * (KS / 32) + kc;
                short8 b = *(const short8*)(Bp + (((long)nt * (K / 32) + kcg) * 64 + lane) * 8);
                acc[ai] = __builtin_amdgcn_mfma_f32_16x16x32_bf16(a, b, acc[ai], 0, 0, 0);
            }
            if (KB == 1) {
                int col = nt * 16 + lrow;
                float bv = bias[col];
#pragma unroll
                for (int r = 0; r < 4; ++r) {
                    int row = m0 + wave * 16 + quad * 4 + r;
                    if (row < M) {
                        float v = acc[0][r] + bv;
                        if (RELU && v < 0.f) v = 0.f;
                        C[(long)row * ldc + col] = v;
                    }
                }
            }
        }
    }
    if (KB > 1) {
#pragma unroll
        for (int nt = 0; nt < NT; ++nt) {
            int col = nt * 16 + lrow;
            float bv = bias[col];
#pragma unroll
            for (int r = 0; r < 4; ++r) {
                int row = m0 + wave * 16 + quad * 4 + r;
                if (row < M) {
                    float v = acc[nt][r] + bv;
                    if (RELU && v < 0.f) v = 0.f;
                    C[(long)row * ldc + col] = v;
                }
            }
        }
    }
}

// ---------------- per-node causal attention T=8,H=8,HD=16 ----------------
__global__ void attn_kernel(const float* __restrict__ qkv, float* __restrict__ o, int N) {
    int idx = blockIdx.x * blockDim.x + threadIdx.x;
    if (idx >= N * kH * kT) return;
    int n = idx / (kH * kT);
    int r = idx % (kH * kT);
    int h = r / kT, s = r % kT;
    const float* qp = qkv + ((long)s * N + n) * 384 + h * kHD;
    float q[kHD];
#pragma unroll
    for (int j = 0; j < kHD; ++j) q[j] = qp[j];
    float sc[kT];
    float mx = -1e30f;
    for (int m = 0; m <= s; ++m) {
        const float* kp = qkv + ((long)m * N + n) * 384 + 128 + h * kHD;
        float dacc = 0.f;
#pragma unroll
        for (int j = 0; j < kHD; ++j) dacc += q[j] * kp[j];
        dacc *= 0.25f;
        sc[m] = dacc;
        mx = fmaxf(mx, dacc);
    }
    float sum = 0.f;
    for (int m = 0; m <= s; ++m) { sc[m] = expf(sc[m] - mx); sum += sc[m]; }
    float inv = 1.f / sum;
    float ov[kHD];
#pragma unroll
    for (int j = 0; j < kHD; ++j) ov[j] = 0.f;
    for (int m = 0; m <= s; ++m) {
        const float* vp = qkv + ((long)m * N + n) * 384 + 256 + h * kHD;
        float am = sc[m] * inv;
#pragma unroll
        for (int j = 0; j < kHD; ++j) ov[j] += am * vp[j];
    }
    float* op = o + ((long)s * N + n) * kD + h * kHD;
#pragma unroll
    for (int j = 0; j < kHD; ++j) op[j] = ov[j];
}

// ---------------- x = LN(x + y) * g + b ----------------
__global__ void res_ln_kernel(float* __restrict__ x, const float* __restrict__ y,
                              const float* __restrict__ g, const float* __restrict__ b) {
    int d = threadIdx.x;
    long o = (long)blockIdx.x * kD + d;
    __shared__ float red[kD];
    float v = x[o] + y[o];
    red[d] = v;
    __syncthreads();
    for (int st = 64; st > 0; st >>= 1) { if (d < st) red[d] += red[d + st]; __syncthreads(); }
    float mu = red[0] * (1.f / kD);
    __syncthreads();
    float dv = v - mu;
    red[d] = dv * dv;
    __syncthreads();
    for (int st = 64; st > 0; st >>= 1) { if (d < st) red[d] += red[d + st]; __syncthreads(); }
    float var = red[0] * (1.f / kD);
    x[o] = dv * rsqrtf(var + 1e-5f) * g[d] + b[d];
}

// ---------------- scores: fp32 64x64 tile, 4x4 per thread, transposed LDS ----------------
__global__ __launch_bounds__(256) void score_kernel(const float* __restrict__ A, const float* __restrict__ B,
                                                    float* __restrict__ out, int M, int Nn) {
    int t = blockIdx.z;
    const float* At = A + (long)t * M * kD;
    const float* Bt = B + (long)t * Nn * kD;
    float* Ot = out + (long)t * M * Nn;
    int bm = blockIdx.y * 64, bn = blockIdx.x * 64;
    int tid = threadIdx.x;
    int cx = tid & 15, ry = tid >> 4;   // 16x16 threads, each 4x4 outputs
    __shared__ float As[32 * 68];       // [k][m], pitch 68 (272B, 16B-aligned)
    __shared__ float Bs[32 * 68];       // [k][n]
    float acc[4][4];
#pragma unroll
    for (int i = 0; i < 4; ++i)
#pragma unroll
        for (int j = 0; j < 4; ++j) acc[i][j] = 0.f;

    for (int k0 = 0; k0 < kD; k0 += 32) {
        __syncthreads();
        for (int i = tid; i < 64 * 32; i += 256) {
            int r = i >> 5, c = i & 31;
            int am = bm + r;
            As[c * 68 + r] = (am < M) ? At[(long)am * kD + k0 + c] : 0.f;
            int bnn = bn + r;
            Bs[c * 68 + r] = (bnn < Nn) ? Bt[(long)bnn * kD + k0 + c] : 0.f;
        }
        __syncthreads();
#pragma unroll 4
        for (int k = 0; k < 32; ++k) {
            float4 a = *(const float4*)&As[k * 68 + ry * 4];
            float4 b = *(const float4*)&Bs[k * 68 + cx * 4];
            float av[4] = {a.x, a.y, a.z, a.w};
            float bv[4] = {b.x, b.y, b.z, b.w};
#pragma unroll
            for (int i = 0; i < 4; ++i)
#pragma unroll
                for (int j = 0; j < 4; ++j) acc[i][j] += av[i] * bv[j];
        }
    }
#pragma unroll
    for (int i = 0; i < 4; ++i) {
        int om = bm + ry * 4 + i;
        if (om >= M) continue;
#pragma unroll
        for (int j = 0; j < 4; ++j) {
            int on = bn + cx * 4 + j;
            if (on < Nn) Ot[(long)om * Nn + on] = acc[i][j];
        }
    }
}

// ---------------- labels scatter ----------------
__global__ void label_kernel(const int* __restrict__ s_, const int* __restrict__ d_,
                             float* __restrict__ out, int Nn) {
    int idx = blockIdx.x * blockDim.x + threadIdx.x;
    if (idx >= kT * kE) return;
    int t = idx >> 14;
    int s = s_[idx], dd = d_[idx];
    out[(long)t * kNADM * Nn + (long)s * Nn + dd] = 1.0f;
}

extern "C" void kernel_launch(void* const* d_in, const int* in_sizes, int n_in,
                              void* d_out, int out_size, void* d_ws, size_t ws_size,
                              hipStream_t stream) {
    const float* x_adm       = (const float*)d_in[0];
    const float* x_lab       = (const float*)d_in[1];
    const float* x_drug      = (const float*)d_in[2];
    const float* edge_x_did  = (const float*)d_in[3];
    const float* edge_x_took = (const float*)d_in[4];
    const float* w_proj_adm  = (const float*)d_in[5];
    const float* b_proj_adm  = (const float*)d_in[6];
    const float* w_proj_lab  = (const float*)d_in[7];
    const float* b_proj_lab  = (const float*)d_in[8];
    const float* w_proj_drug = (const float*)d_in[9];
    const float* b_proj_drug = (const float*)d_in[10];
    const float* w_proj_e    = (const float*)d_in[11];
    const float* b_proj_e    = (const float*)d_in[12];
    const float* w_proj_e4d  = (const float*)d_in[13];
    const float* b_proj_e4d  = (const float*)d_in[14];
    const float* emb_lab     = (const float*)d_in[15];
    const float* emb_drug    = (const float*)d_in[16];
    const float* gnn_w       = (const float*)d_in[17];
    const float* gnn_b       = (const float*)d_in[18];
    const float* dec_sa_in_w  = (const float*)d_in[19];
    const float* dec_sa_in_b  = (const float*)d_in[20];
    const float* dec_sa_out_w = (const float*)d_in[21];
    const float* dec_sa_out_b = (const float*)d_in[22];
    const float* dec_ca_in_w  = (const float*)d_in[23];
    const float* dec_ca_in_b  = (const float*)d_in[24];
    const float* dec_ca_out_w = (const float*)d_in[25];
    const float* dec_ca_out_b = (const float*)d_in[26];
    const float* dec_ff1_w    = (const float*)d_in[27];
    const float* dec_ff1_b    = (const float*)d_in[28];
    const float* dec_ff2_w    = (const float*)d_in[29];
    const float* dec_ff2_b    = (const float*)d_in[30];
    const float* dec_ln1_w    = (const float*)d_in[31];
    const float* dec_ln1_b    = (const float*)d_in[32];
    const float* dec_ln2_w    = (const float*)d_in[33];
    const float* dec_ln2_b    = (const float*)d_in[34];
    const float* dec_ln3_w    = (const float*)d_in[35];
    const float* dec_ln3_b    = (const float*)d_in[36];
    const int* node_id_lab  = (const int*)d_in[37];
    const int* node_id_drug = (const int*)d_in[38];
    const int* src_did      = (const int*)d_in[39];
    const int* dst_did      = (const int*)d_in[40];
    const int* src_took     = (const int*)d_in[41];
    const int* dst_took     = (const int*)d_in[42];
    const int* lbl_src_did  = (const int*)d_in[43];
    const int* lbl_dst_did  = (const int*)d_in[44];
    const int* lbl_src_took = (const int*)d_in[45];
    const int* lbl_dst_took = (const int*)d_in[46];

    float* out_f = (float*)d_out;
    const long SC1 = (long)kT * kNADM * kNLAB;    // 12,337,152
    const long SC2 = (long)kT * kNADM * kNDRUG;   // 70,352,896
    float* out_scores  = out_f;
    float* out_labels  = out_f + SC1;
    float* out_scores4 = out_f + 2 * SC1;
    float* out_labels4 = out_f + 2 * SC1 + SC2;

    // scratch arena inside d_out (scores4 + labels4 regions; both dead until the end)
    float* SCR = out_scores4;                     // 70.3M floats, peak use 26.4M
    float* Sp  = out_labels4;
    const long SA_SZ = (long)kT * kNADM * kD;     // 2,097,152
    const long SL_SZ = (long)kT * kNLAB * kD;     //   771,072
    const long SD_SZ = (long)kT * kNDRUG * kD;    // 4,397,056
    float* Sa = Sp;
    float* Sl = Sa + SA_SZ;
    float* Sd = Sl + SL_SZ;                       // ends 7,265,280
    // packed bf16 decoder weights (shorts), after Sd, 16B aligned
    short* pk_base = (short*)(Sp + 7265288);
    const long PS_SA_IN = 18L * 128 * 384;        // shorts per array
    const long PS_SA_OUT = 18L * 128 * 128;
    const long PS_CA_IN = PS_SA_IN;
    const long PS_CA_OUT = PS_SA_OUT;
    const long PS_FF1 = 18L * 128 * 512;
    const long PS_FF2 = 18L * 512 * 128;
    short* pk_sa_in  = pk_base;
    short* pk_sa_out = pk_sa_in + PS_SA_IN;
    short* pk_ca_in  = pk_sa_out + PS_SA_OUT;
    short* pk_ca_out = pk_ca_in + PS_CA_IN;
    short* pk_ff1    = pk_ca_out + PS_CA_OUT;
    short* pk_ff2    = pk_ff1 + PS_FF1;           // ends ~9.62M floats < SC2

    // GNN-phase aliases in SCR
    float* h0a = SCR;
    float* h0l = h0a + (long)kNADM * kD;
    float* h0d = h0l + (long)kNLAB * kD;
    float* Ta  = h0d + (long)kNDRUG * kD;
    float* Tl  = Ta + SA_SZ;
    float* Td  = Tl + SL_SZ;
    float* msgA1 = Td + SD_SZ;
    float* msgA2 = msgA1 + SA_SZ;
    float* msgL  = msgA2 + SA_SZ;
    float* msgD  = msgL + SL_SZ;
    const long MSG_SZ = SA_SZ * 2 + SL_SZ + SD_SZ;
    // decoder-phase aliases in SCR
    float* bigbuf = SCR;                          // up to TN*512
    float* obuf   = bigbuf + (long)kT * kNDRUG * kFF;
    float* membuf = obuf + SD_SZ;                 // ends 26,382,336 < SC2

    // ---- pack decoder weights to bf16 fragment order (once per launch) ----
    {
        long t1 = PS_SA_IN;
        pack_w<<<(int)((t1 + 255) / 256), 256, 0, stream>>>(dec_sa_in_w, pk_sa_in, 128, 384, t1);
        long t2 = PS_SA_OUT;
        pack_w<<<(int)((t2 + 255) / 256), 256, 0, stream>>>(dec_sa_out_w, pk_sa_out, 128, 128, t2);
        pack_w<<<(int)((t1 + 255) / 256), 256, 0, stream>>>(dec_ca_in_w, pk_ca_in, 128, 384, t1);
        pack_w<<<(int)((t2 + 255) / 256), 256, 0, stream>>>(dec_ca_out_w, pk_ca_out, 128, 128, t2);
        long t3 = PS_FF1;
        pack_w<<<(int)((t3 + 255) / 256), 256, 0, stream>>>(dec_ff1_w, pk_ff1, 128, 512, t3);
        pack_w<<<(int)((t3 + 255) / 256), 256, 0, stream>>>(dec_ff2_w, pk_ff2, 512, 128, t3);
    }

    // ---- node projections ----
    proj_kernel<<<kNADM,  kD, 0, stream>>>(x_adm,  8, w_proj_adm,  b_proj_adm,  nullptr,  nullptr,      h0a);
    proj_kernel<<<kNLAB,  kD, 0, stream>>>(x_lab,  2, w_proj_lab,  b_proj_lab,  emb_lab,  node_id_lab,  h0l);
    proj_kernel<<<kNDRUG, kD, 0, stream>>>(x_drug, 8, w_proj_drug, b_proj_drug, emb_drug, node_id_drug, h0d);

    // ---- GNN: 2 layers ----
    for (int l = 0; l < 2; ++l) {
        zero_kernel<<<(int)((MSG_SZ + 255) / 256), 256, 0, stream>>>(msgA1, MSG_SZ);
        const float *ha, *hl, *hd;
        long sa, sl, sd;
        float *oa, *ol, *od;
        if (l == 0) { ha = h0a; hl = h0l; hd = h0d; sa = sl = sd = 0;
                      oa = Ta; ol = Tl; od = Td; }
        else        { ha = Ta; hl = Tl; hd = Td;
                      sa = (long)kNADM * kD; sl = (long)kNLAB * kD; sd = (long)kNDRUG * kD;
                      oa = Sa; ol = Sl; od = Sd; }
        msg_kernel<<<kT * kE, kD, 0, stream>>>(edge_x_did, 2, src_did, dst_did, w_proj_e, b_proj_e,
                                               ha, sa, hl, sl, msgL, kNLAB, msgA1, kNADM);
        msg_kernel<<<kT * kE, kD, 0, stream>>>(edge_x_took, 7, src_took, dst_took, w_proj_e4d, b_proj_e4d,
                                               ha, sa, hd, sd, msgD, kNDRUG, msgA2, kNADM);
        gnn_dense_adm<<<kT * kNADM, kD, 0, stream>>>(msgA1, msgA2, ha, sa, gnn_w, gnn_b, l, oa);
        gnn_dense<<<kT * kNLAB,  kD, 0, stream>>>(msgL, hl, sl, gnn_w, gnn_b, l, 0, ol, kNLAB);
        gnn_dense<<<kT * kNDRUG, kD, 0, stream>>>(msgD, hd, sd, gnn_w, gnn_b, l, 2, od, kNDRUG);
    }

    // ---- positional encoding ----
    pe_kernel<<<kT * kNADM,  kD, 0, stream>>>(Sa, kNADM);
    pe_kernel<<<kT * kNLAB,  kD, 0, stream>>>(Sl, kNLAB);
    pe_kernel<<<kT * kNDRUG, kD, 0, stream>>>(Sd, kNDRUG);

    // ---- decoders (MFMA GEMMs) ----
    auto run_decoder = [&](int i, float* X, int N) {
        int TN = kT * N;
        long n128 = (long)TN * kD;
        int gT = (TN + 63) / 64;
        copy_kernel<<<(int)((n128 + 255) / 256), 256, 0, stream>>>(membuf, X, n128);
        for (int l = 0; l < kL; ++l) {
            long w = (long)i * kL + l;
            // self-attention
            mfma_gemm<128, 384, false><<<gT, 256, 0, stream>>>(X, pk_sa_in + w * 49152,
                    dec_sa_in_b + w * 384, bigbuf, 384, TN);
            attn_kernel<<<(N * kH * kT + 255) / 256, 256, 0, stream>>>(bigbuf, obuf, N);
            mfma_gemm<128, 128, false><<<gT, 256, 0, stream>>>(obuf, pk_sa_out + w * 16384,
                    dec_sa_out_b + w * kD, bigbuf, kD, TN);
            res_ln_kernel<<<TN, kD, 0, stream>>>(X, bigbuf, dec_ln1_w + w * kD, dec_ln1_b + w * kD);
            // cross-attention
            mfma_gemm<128, 128, false><<<gT, 256, 0, stream>>>(X, pk_ca_in + w * 49152,
                    dec_ca_in_b + w * 384, bigbuf, 384, TN);
            mfma_gemm<128, 256, false><<<gT, 256, 0, stream>>>(membuf, pk_ca_in + w * 49152 + 16384,
                    dec_ca_in_b + w * 384 + 128, bigbuf + 128, 384, TN);
            attn_kernel<<<(N * kH * kT + 255) / 256, 256, 0, stream>>>(bigbuf, obuf, N);
            mfma_gemm<128, 128, false><<<gT, 256, 0, stream>>>(obuf, pk_ca_out + w * 16384,
                    dec_ca_out_b + w * kD, bigbuf, kD, TN);
            res_ln_kernel<<<TN, kD, 0, stream>>>(X, bigbuf, dec_ln2_w + w * kD, dec_ln2_b + w * kD);
            // feed-forward
            mfma_gemm<128, 512, true><<<gT, 256, 0, stream>>>(X, pk_ff1 + w * 65536,
                    dec_ff1_b + w * kFF, bigbuf, kFF, TN);
            mfma_gemm<512, 128, false><<<gT, 256, 0, stream>>>(bigbuf, pk_ff2 + w * 65536,
                    dec_ff2_b + w * kD, obuf, kD, TN);
            res_ln_kernel<<<TN, kD, 0, stream>>>(X, obuf, dec_ln3_w + w * kD, dec_ln3_b + w * kD);
        }
    };

    run_decoder(0, Sa, kNADM);
    run_decoder(1, Sl, kNLAB);
    run_decoder(2, Sd, kNDRUG);

    // scores (adm x lab)
    score_kernel<<<dim3((kNLAB + 63) / 64, kNADM / 64, kT), 256, 0, stream>>>(Sa, Sl, out_scores, kNADM, kNLAB);
    // labels (did)
    hipMemsetAsync((void*)out_labels, 0, (size_t)SC1 * sizeof(float), stream);
    label_kernel<<<(kT * kE + 255) / 256, 256, 0, stream>>>(lbl_src_did, lbl_dst_did, out_labels, kNLAB);
    // scores4 (adm x drug): writes over SCR (dead), reads Sa/Sd — disjoint
    score_kernel<<<dim3((kNDRUG + 63) / 64, kNADM / 64, kT), 256, 0, stream>>>(Sa, Sd, out_scores4, kNADM, kNDRUG);
    // labels4 LAST (memset clobbers Sa/Sl/Sd + packed weights, all dead now)
    hipMemsetAsync((void*)out_labels4, 0, (size_t)SC2 * sizeof(float), stream);
    label_kernel<<<(kT * kE + 255) / 256, 256, 0, stream>>>(lbl_src_took, lbl_dst_took, out_labels4, kNDRUG);

    (void)in_sizes; (void)n_in; (void)out_size; (void)d_ws; (void)ws_size;
}